// Round 25
// baseline (57.326 us; speedup 1.0000x reference)
//
#include <hip/hip_runtime.h>
#include <hip/hip_bf16.h>
#include <cstdint>

static constexpr int H  = 2048;
static constexpr int W  = 2048;
static constexpr int NG = 65536;
static constexpr int R  = 16;          // patch = 33x33
static constexpr int TS = 32;          // tile size
static constexpr int TX = W / TS;      // 64
static constexpr int NT = TX * (H / TS);  // 4096 tiles
static constexpr int MAXQ  = 64;       // slots per top-left tile (mean 16, 12 sigma)
static constexpr int SPTOT = 160;      // staged records cap/tile (mean 66, ~11 sigma)
static constexpr int CPAD  = 16;       // u32 per counter -> 64B line each
static constexpr size_t HW = (size_t)H * W;

typedef float v2f __attribute__((ext_vector_type(2)));

__device__ __forceinline__ uint32_t bf16bits(float x) {
    return (uint32_t)__bfloat16_as_ushort(__float2bfloat16(x));
}

// Zero the 256KB counter array at full width (~2us).
__global__ __launch_bounds__(256) void gf_zero(uint4* __restrict__ p)
{
    p[blockIdx.x * 256 + threadIdx.x] = make_uint4(0u, 0u, 0u, 0u);
}

// Kernel A (r21-proven): TOP-LEFT-ONLY binning — 1 atomic + 1 list write per
// gaussian; tile t's full list = G(t) u G(left) u G(up) u G(upleft).
// A=(mx,my,iaK=K/l11,dwK=K/l22) B=(ddK=K*l21/(l11*l22), wr, wi, uu2=exp2(-4*dwK^2))
__global__ __launch_bounds__(128) void gf_bin(
    const float* __restrict__ means,
    const float* __restrict__ chol,
    const float* __restrict__ weights,
    uint32_t* __restrict__ cnt,
    uint32_t* __restrict__ lst,
    float4* __restrict__ par)
{
    const int n = blockIdx.x * 128 + threadIdx.x;
    if (n >= NG) return;

    const float2 mn = ((const float2*)means)[n];
    const float2 wt = ((const float2*)weights)[n];
    const float mx = mn.x, my = mn.y;
    const float c0  = chol[3 * n + 0];
    const float l21 = chol[3 * n + 1];
    const float c2  = chol[3 * n + 2];

    // softplus(x) = max(x,0) + log1p(exp(-|x|)); short series (z small here)
    auto softp = [](float x) {
        const float z  = __expf(-fabsf(x));
        const float lp = z - 0.5f * z * z + 0.33333333f * z * z * z;
        return fmaxf(x, 0.0f) + lp;
    };
    const float l11 = 0.5f + softp(c0);
    const float l22 = 0.5f + softp(c2);

    constexpr float KK = 0.84932180028801905f;   // sqrt(0.5*log2(e))
    const float iaK = KK / l11;
    const float dwK = KK / l22;
    const float ddK = KK * l21 / (l11 * l22);
    const float uu2 = exp2f(-4.0f * dwK * dwK);

    par[2 * n + 0] = make_float4(mx, my, iaK, dwK);
    par[2 * n + 1] = make_float4(ddK, wt.x, wt.y, uu2);

    const int tlx = (int)floorf(mx) - R;
    const int tly = (int)floorf(my) - R;
    const int tx0 = max(tlx, 0) >> 5;
    const int ty0 = max(tly, 0) >> 5;
    const int q = ty0 * TX + tx0;

    const uint32_t slot = atomicAdd(&cnt[(size_t)q * CPAD], 1u);
    if (slot < MAXQ) lst[(size_t)q * MAXQ + slot] = (uint32_t)n;
}

// Kernel B (r22-proven structure + early epilogue loads): 4096 blocks
// (1/tile) x 256 thr = 4 waves, each a QUARTILE of the concatenated
// 4-neighbor list (setup once per pair). Two-segment merge tree; wave0
// epilogue. NEW: wave0 issues its 16 even-row init-plane loads BEFORE the
// merge barriers (~300cyc of merge hides the HBM/L2 latency previously
// exposed serially in the epilogue). Packed v2f recurrence G*=T, T*=U.
// No per-lane predicates (tails <= ~6e-4; absmax 0.0625 for 16 rounds).
__global__ __launch_bounds__(256, 8) void gf_tiles(
    const float4* __restrict__ par,
    const uint32_t* __restrict__ cnt,
    const uint32_t* __restrict__ lst,
    const float* __restrict__ init_re,
    const float* __restrict__ init_im,
    const float* __restrict__ rs,
    uint32_t* __restrict__ out)
{
    __shared__ float4 sp[2 * SPTOT];             // 5.1 KB records
    __shared__ float  mrg[2][64 * 17];           // 8.7 KB, two segments

    const int tile = blockIdx.x;
    const int wid  = threadIdx.x >> 6;           // 0..3 (list quartile)
    const int lane = threadIdx.x & 63;
    const int tx = tile & (TX - 1), ty = tile >> 6;

    // 4 source lists: (ty-1,tx-1), (ty-1,tx), (ty,tx-1), (ty,tx)
    const int okL = tx > 0, okU = ty > 0;
    const int q0 = (ty - 1) * TX + (tx - 1);
    const int q1 = (ty - 1) * TX + tx;
    const int q2 = ty * TX + (tx - 1);
    const int q3 = tile;
    const int c0 = (okL & okU) ? min((int)cnt[(size_t)q0 * CPAD], MAXQ) : 0;
    const int c1 = okU         ? min((int)cnt[(size_t)q1 * CPAD], MAXQ) : 0;
    const int c2 = okL         ? min((int)cnt[(size_t)q2 * CPAD], MAXQ) : 0;
    const int c3 =               min((int)cnt[(size_t)q3 * CPAD], MAXQ);
    const int p1 = c0, p2 = c0 + c1, p3 = c0 + c1 + c2;
    const int m  = min(p3 + c3, SPTOT);

    const int jb = (m * wid) >> 2;               // this wave's quartile
    const int je = (m * (wid + 1)) >> 2;

    // wave-private staging of this wave's range of the concatenated list
    for (int i = jb + lane; i < je; i += 64) {
        int q, off;
        if      (i < p1) { q = q0; off = i; }
        else if (i < p2) { q = q1; off = i - p1; }
        else if (i < p3) { q = q2; off = i - p2; }
        else             { q = q3; off = i - p3; }
        const uint32_t n = lst[(size_t)q * MAXQ + off];
        sp[2 * i + 0] = par[2 * (size_t)n + 0];
        sp[2 * i + 1] = par[2 * (size_t)n + 1];
    }

    const int gx0 = tx * TS, gy0 = ty * TS;
    const int col  = lane & 31;
    const int row0 = (lane >> 5) * 16;           // 0 or 16
    const int gx = gx0 + col;
    const float fx  = (float)gx;
    const float fy0 = (float)(gy0 + row0);

    v2f aR[8], aI[8];
#pragma unroll
    for (int i = 0; i < 8; ++i) { aR[i] = (v2f)(0.0f); aI[i] = (v2f)(0.0f); }

    for (int j = jb; j < je; ++j) {
        const float4 A = sp[2 * j + 0];
        const float4 B = sp[2 * j + 1];

        const float dx  = fx  - A.x;
        const float dy0 = fy0 - A.y;
        const float u1  = A.z * dx;
        const float nb  = u1 * u1;
        const float w0  = fmaf(A.w, dy0, -(B.x * dx));
        const float w1  = w0 + A.w;
        const float g0  = __builtin_amdgcn_exp2f(-fmaf(w0, w0, nb));
        const float g1  = __builtin_amdgcn_exp2f(-fmaf(w1, w1, nb));
        const float tau0 = __builtin_amdgcn_exp2f(-4.0f * A.w * w1);
        v2f G = { g0, g1 };
        v2f T = { tau0, tau0 * B.w };
        const v2f U  = (v2f)(B.w * B.w);
        const v2f WR = (v2f)(B.y);
        const v2f WI = (v2f)(B.z);

#pragma unroll
        for (int i = 0; i < 8; ++i) {
            aR[i] = __builtin_elementwise_fma(WR, G, aR[i]);
            aI[i] = __builtin_elementwise_fma(WI, G, aI[i]);
            G *= T;
            T *= U;
        }
    }

    // EARLY epilogue loads (wave0's even rows): issued before the merge
    // barriers so the ~6-barrier merge hides their HBM/L2 latency.
    float pre_re[8], pre_im[8];
    if (wid == 0) {
#pragma unroll
        for (int i = 0; i < 8; ++i) {
            const size_t pix0 = (size_t)(gy0 + row0 + 2 * i) * W + gx;
            pre_re[i] = init_re[pix0];
            pre_im[i] = init_im[pix0];
        }
    }

    // merge tree: (w1->w0, w3->w2) in parallel segments, then w2->w0
    float* s0 = mrg[0] + lane * 17;
    float* s1 = mrg[1] + lane * 17;

    if (wid == 1) {
#pragma unroll
        for (int i = 0; i < 8; ++i) { s0[2*i] = aR[i].x; s0[2*i+1] = aR[i].y; }
    } else if (wid == 3) {
#pragma unroll
        for (int i = 0; i < 8; ++i) { s1[2*i] = aR[i].x; s1[2*i+1] = aR[i].y; }
    }
    __syncthreads();
    if (wid == 0) {
#pragma unroll
        for (int i = 0; i < 8; ++i) { aR[i].x += s0[2*i]; aR[i].y += s0[2*i+1]; }
    } else if (wid == 2) {
#pragma unroll
        for (int i = 0; i < 8; ++i) { aR[i].x += s1[2*i]; aR[i].y += s1[2*i+1]; }
    }
    __syncthreads();
    if (wid == 1) {
#pragma unroll
        for (int i = 0; i < 8; ++i) { s0[2*i] = aI[i].x; s0[2*i+1] = aI[i].y; }
    } else if (wid == 3) {
#pragma unroll
        for (int i = 0; i < 8; ++i) { s1[2*i] = aI[i].x; s1[2*i+1] = aI[i].y; }
    }
    __syncthreads();
    if (wid == 0) {
#pragma unroll
        for (int i = 0; i < 8; ++i) { aI[i].x += s0[2*i]; aI[i].y += s0[2*i+1]; }
    } else if (wid == 2) {
#pragma unroll
        for (int i = 0; i < 8; ++i) { aI[i].x += s1[2*i]; aI[i].y += s1[2*i+1]; }
    }
    __syncthreads();
    if (wid == 2) {
#pragma unroll
        for (int i = 0; i < 8; ++i) {
            s0[2*i] = aR[i].x; s0[2*i+1] = aR[i].y;
            s1[2*i] = aI[i].x; s1[2*i+1] = aI[i].y;
        }
    }
    __syncthreads();
    if (wid == 0) {
#pragma unroll
        for (int i = 0; i < 8; ++i) {
            aR[i].x += s0[2*i]; aR[i].y += s0[2*i+1];
            aI[i].x += s1[2*i]; aI[i].y += s1[2*i+1];
        }

        const float s = rs[0];
#pragma unroll
        for (int i = 0; i < 8; ++i) {
            const size_t pix0 = (size_t)(gy0 + row0 + 2 * i) * W + gx;
            const size_t pix1 = pix0 + W;
            out[pix0] = bf16bits(fmaf(s, aR[i].x, pre_re[i]))
                      | (bf16bits(fmaf(s, aI[i].x, pre_im[i])) << 16);
            out[pix1] = bf16bits(fmaf(s, aR[i].y, init_re[pix1]))
                      | (bf16bits(fmaf(s, aI[i].y, init_im[pix1])) << 16);
        }
    }
}

extern "C" void kernel_launch(void* const* d_in, const int* in_sizes, int n_in,
                              void* d_out, int out_size, void* d_ws, size_t ws_size,
                              hipStream_t stream) {
    // Inputs arrive NAME-SORTED: chol, init_im, init_re, means, residual_scale,
    // weights (verified round 6). Classify by element count.
    const float* means   = nullptr;
    const float* chol    = nullptr;
    const float* weights = nullptr;
    const float* planeA  = nullptr;   // init_im (first H*W)
    const float* planeB  = nullptr;   // init_re (second H*W)
    const float* rs      = nullptr;

    int nSmall = 0, nBig = 0;
    for (int i = 0; i < n_in; ++i) {
        const int sz = in_sizes[i];
        const float* p = (const float*)d_in[i];
        if      (sz == 3 * NG)  chol = p;
        else if (sz == 1)       rs = p;
        else if (sz == 2 * NG)  { if (nSmall++ == 0) means = p; else weights = p; }
        else if (sz == (int)HW) { if (nBig++   == 0) planeA = p; else planeB = p; }
    }
    if (!means || !chol || !weights || !planeA || !planeB || !rs) return;

    const float* init_im = planeA;
    const float* init_re = planeB;

    // ws layout: cnt (NT*64B = 256KB) | lst (NT*MAXQ*4B = 1MB) | par (2MB)
    uint8_t* w8 = (uint8_t*)d_ws;
    uint32_t* cnt = (uint32_t*)w8;
    uint32_t* lst = (uint32_t*)(w8 + (size_t)NT * CPAD * sizeof(uint32_t));
    float4*   par = (float4*)(w8 + (size_t)NT * CPAD * sizeof(uint32_t)
                                 + (size_t)NT * MAXQ * sizeof(uint32_t));

    gf_zero<<<(NT * CPAD) / (4 * 256), 256, 0, stream>>>((uint4*)cnt);

    gf_bin<<<NG / 128, 128, 0, stream>>>(means, chol, weights, cnt, lst, par);
    gf_tiles<<<NT, 256, 0, stream>>>(par, cnt, lst, init_re, init_im, rs,
                                     (uint32_t*)d_out);
}

// Round 26
// 49.346 us; speedup vs baseline: 1.1617x; 1.1617x over previous
//
#include <hip/hip_runtime.h>
#include <hip/hip_bf16.h>
#include <cstdint>

static constexpr int H  = 2048;
static constexpr int W  = 2048;
static constexpr int NG = 65536;
static constexpr int R  = 16;          // patch = 33x33
static constexpr int TS = 32;          // tile size
static constexpr int TX = W / TS;      // 64
static constexpr int NT = TX * (H / TS);  // 4096 tiles
static constexpr int MAXQ  = 64;       // slots per top-left tile (mean 16, 12 sigma)
static constexpr int SPTOT = 160;      // staged records cap/tile (mean 66, ~11 sigma)
static constexpr int CPAD  = 16;       // u32 per counter -> 64B line each
static constexpr size_t HW = (size_t)H * W;

typedef float v2f __attribute__((ext_vector_type(2)));

__device__ __forceinline__ uint32_t bf16bits(float x) {
    return (uint32_t)__bfloat16_as_ushort(__float2bfloat16(x));
}

// Zero the 256KB counter array at full width (~2us).
__global__ __launch_bounds__(256) void gf_zero(uint4* __restrict__ p)
{
    p[blockIdx.x * 256 + threadIdx.x] = make_uint4(0u, 0u, 0u, 0u);
}

// Kernel A (r21-proven): TOP-LEFT-ONLY binning — 1 atomic + 1 list write per
// gaussian; tile t's full list = G(t) u G(left) u G(up) u G(upleft).
// A=(mx,my,iaK=K/l11,dwK=K/l22) B=(ddK=K*l21/(l11*l22), wr, wi, uu2=exp2(-4*dwK^2))
__global__ __launch_bounds__(128) void gf_bin(
    const float* __restrict__ means,
    const float* __restrict__ chol,
    const float* __restrict__ weights,
    uint32_t* __restrict__ cnt,
    uint32_t* __restrict__ lst,
    float4* __restrict__ par)
{
    const int n = blockIdx.x * 128 + threadIdx.x;
    if (n >= NG) return;

    const float2 mn = ((const float2*)means)[n];
    const float2 wt = ((const float2*)weights)[n];
    const float mx = mn.x, my = mn.y;
    const float c0  = chol[3 * n + 0];
    const float l21 = chol[3 * n + 1];
    const float c2  = chol[3 * n + 2];

    // softplus(x) = max(x,0) + log1p(exp(-|x|)); short series (z small here)
    auto softp = [](float x) {
        const float z  = __expf(-fabsf(x));
        const float lp = z - 0.5f * z * z + 0.33333333f * z * z * z;
        return fmaxf(x, 0.0f) + lp;
    };
    const float l11 = 0.5f + softp(c0);
    const float l22 = 0.5f + softp(c2);

    constexpr float KK = 0.84932180028801905f;   // sqrt(0.5*log2(e))
    const float iaK = KK / l11;
    const float dwK = KK / l22;
    const float ddK = KK * l21 / (l11 * l22);
    const float uu2 = exp2f(-4.0f * dwK * dwK);

    par[2 * n + 0] = make_float4(mx, my, iaK, dwK);
    par[2 * n + 1] = make_float4(ddK, wt.x, wt.y, uu2);

    const int tlx = (int)floorf(mx) - R;
    const int tly = (int)floorf(my) - R;
    const int tx0 = max(tlx, 0) >> 5;
    const int ty0 = max(tly, 0) >> 5;
    const int q = ty0 * TX + tx0;

    const uint32_t slot = atomicAdd(&cnt[(size_t)q * CPAD], 1u);
    if (slot < MAXQ) lst[(size_t)q * MAXQ + slot] = (uint32_t)n;
}

// Kernel B (r22-proven, best-measured): 4096 blocks (1/tile) x 256 thr =
// 4 waves, each taking a QUARTILE of the tile's concatenated 4-neighbor
// list (setup once per pair). Two-segment parallel merge tree (w1->w0,
// w3->w2, then w2->w0); wave0 epilogue. Lane = col x row-half; packed v2f
// row recurrence G*=T, T*=U. No per-lane predicates (tails <= ~6e-4;
// absmax 0.0625 for 17 rounds).
__global__ __launch_bounds__(256, 8) void gf_tiles(
    const float4* __restrict__ par,
    const uint32_t* __restrict__ cnt,
    const uint32_t* __restrict__ lst,
    const float* __restrict__ init_re,
    const float* __restrict__ init_im,
    const float* __restrict__ rs,
    uint32_t* __restrict__ out)
{
    __shared__ float4 sp[2 * SPTOT];             // 5.1 KB records
    __shared__ float  mrg[2][64 * 17];           // 8.7 KB, two segments

    const int tile = blockIdx.x;
    const int wid  = threadIdx.x >> 6;           // 0..3 (list quartile)
    const int lane = threadIdx.x & 63;
    const int tx = tile & (TX - 1), ty = tile >> 6;

    // 4 source lists: (ty-1,tx-1), (ty-1,tx), (ty,tx-1), (ty,tx)
    const int okL = tx > 0, okU = ty > 0;
    const int q0 = (ty - 1) * TX + (tx - 1);
    const int q1 = (ty - 1) * TX + tx;
    const int q2 = ty * TX + (tx - 1);
    const int q3 = tile;
    const int c0 = (okL & okU) ? min((int)cnt[(size_t)q0 * CPAD], MAXQ) : 0;
    const int c1 = okU         ? min((int)cnt[(size_t)q1 * CPAD], MAXQ) : 0;
    const int c2 = okL         ? min((int)cnt[(size_t)q2 * CPAD], MAXQ) : 0;
    const int c3 =               min((int)cnt[(size_t)q3 * CPAD], MAXQ);
    const int p1 = c0, p2 = c0 + c1, p3 = c0 + c1 + c2;
    const int m  = min(p3 + c3, SPTOT);

    const int jb = (m * wid) >> 2;               // this wave's quartile
    const int je = (m * (wid + 1)) >> 2;

    // wave-private staging of this wave's range of the concatenated list
    for (int i = jb + lane; i < je; i += 64) {
        int q, off;
        if      (i < p1) { q = q0; off = i; }
        else if (i < p2) { q = q1; off = i - p1; }
        else if (i < p3) { q = q2; off = i - p2; }
        else             { q = q3; off = i - p3; }
        const uint32_t n = lst[(size_t)q * MAXQ + off];
        sp[2 * i + 0] = par[2 * (size_t)n + 0];
        sp[2 * i + 1] = par[2 * (size_t)n + 1];
    }

    const int gx0 = tx * TS, gy0 = ty * TS;
    const int col  = lane & 31;
    const int row0 = (lane >> 5) * 16;           // 0 or 16
    const int gx = gx0 + col;
    const float fx  = (float)gx;
    const float fy0 = (float)(gy0 + row0);

    v2f aR[8], aI[8];
#pragma unroll
    for (int i = 0; i < 8; ++i) { aR[i] = (v2f)(0.0f); aI[i] = (v2f)(0.0f); }

    for (int j = jb; j < je; ++j) {
        const float4 A = sp[2 * j + 0];
        const float4 B = sp[2 * j + 1];

        const float dx  = fx  - A.x;
        const float dy0 = fy0 - A.y;
        const float u1  = A.z * dx;
        const float nb  = u1 * u1;
        const float w0  = fmaf(A.w, dy0, -(B.x * dx));
        const float w1  = w0 + A.w;
        const float g0  = __builtin_amdgcn_exp2f(-fmaf(w0, w0, nb));
        const float g1  = __builtin_amdgcn_exp2f(-fmaf(w1, w1, nb));
        const float tau0 = __builtin_amdgcn_exp2f(-4.0f * A.w * w1);
        v2f G = { g0, g1 };
        v2f T = { tau0, tau0 * B.w };
        const v2f U  = (v2f)(B.w * B.w);
        const v2f WR = (v2f)(B.y);
        const v2f WI = (v2f)(B.z);

#pragma unroll
        for (int i = 0; i < 8; ++i) {
            aR[i] = __builtin_elementwise_fma(WR, G, aR[i]);
            aI[i] = __builtin_elementwise_fma(WI, G, aI[i]);
            G *= T;
            T *= U;
        }
    }

    // merge tree: (w1->w0, w3->w2) in parallel segments, then w2->w0
    float* s0 = mrg[0] + lane * 17;
    float* s1 = mrg[1] + lane * 17;

    if (wid == 1) {
#pragma unroll
        for (int i = 0; i < 8; ++i) { s0[2*i] = aR[i].x; s0[2*i+1] = aR[i].y; }
    } else if (wid == 3) {
#pragma unroll
        for (int i = 0; i < 8; ++i) { s1[2*i] = aR[i].x; s1[2*i+1] = aR[i].y; }
    }
    __syncthreads();
    if (wid == 0) {
#pragma unroll
        for (int i = 0; i < 8; ++i) { aR[i].x += s0[2*i]; aR[i].y += s0[2*i+1]; }
    } else if (wid == 2) {
#pragma unroll
        for (int i = 0; i < 8; ++i) { aR[i].x += s1[2*i]; aR[i].y += s1[2*i+1]; }
    }
    __syncthreads();
    if (wid == 1) {
#pragma unroll
        for (int i = 0; i < 8; ++i) { s0[2*i] = aI[i].x; s0[2*i+1] = aI[i].y; }
    } else if (wid == 3) {
#pragma unroll
        for (int i = 0; i < 8; ++i) { s1[2*i] = aI[i].x; s1[2*i+1] = aI[i].y; }
    }
    __syncthreads();
    if (wid == 0) {
#pragma unroll
        for (int i = 0; i < 8; ++i) { aI[i].x += s0[2*i]; aI[i].y += s0[2*i+1]; }
    } else if (wid == 2) {
#pragma unroll
        for (int i = 0; i < 8; ++i) { aI[i].x += s1[2*i]; aI[i].y += s1[2*i+1]; }
    }
    __syncthreads();
    if (wid == 2) {
#pragma unroll
        for (int i = 0; i < 8; ++i) {
            s0[2*i] = aR[i].x; s0[2*i+1] = aR[i].y;
            s1[2*i] = aI[i].x; s1[2*i+1] = aI[i].y;
        }
    }
    __syncthreads();
    if (wid == 0) {
#pragma unroll
        for (int i = 0; i < 8; ++i) {
            aR[i].x += s0[2*i]; aR[i].y += s0[2*i+1];
            aI[i].x += s1[2*i]; aI[i].y += s1[2*i+1];
        }

        const float s = rs[0];
#pragma unroll
        for (int i = 0; i < 8; ++i) {
            const size_t pix0 = (size_t)(gy0 + row0 + 2 * i) * W + gx;
            const size_t pix1 = pix0 + W;
            out[pix0] = bf16bits(fmaf(s, aR[i].x, init_re[pix0]))
                      | (bf16bits(fmaf(s, aI[i].x, init_im[pix0])) << 16);
            out[pix1] = bf16bits(fmaf(s, aR[i].y, init_re[pix1]))
                      | (bf16bits(fmaf(s, aI[i].y, init_im[pix1])) << 16);
        }
    }
}

extern "C" void kernel_launch(void* const* d_in, const int* in_sizes, int n_in,
                              void* d_out, int out_size, void* d_ws, size_t ws_size,
                              hipStream_t stream) {
    // Inputs arrive NAME-SORTED: chol, init_im, init_re, means, residual_scale,
    // weights (verified round 6). Classify by element count.
    const float* means   = nullptr;
    const float* chol    = nullptr;
    const float* weights = nullptr;
    const float* planeA  = nullptr;   // init_im (first H*W)
    const float* planeB  = nullptr;   // init_re (second H*W)
    const float* rs      = nullptr;

    int nSmall = 0, nBig = 0;
    for (int i = 0; i < n_in; ++i) {
        const int sz = in_sizes[i];
        const float* p = (const float*)d_in[i];
        if      (sz == 3 * NG)  chol = p;
        else if (sz == 1)       rs = p;
        else if (sz == 2 * NG)  { if (nSmall++ == 0) means = p; else weights = p; }
        else if (sz == (int)HW) { if (nBig++   == 0) planeA = p; else planeB = p; }
    }
    if (!means || !chol || !weights || !planeA || !planeB || !rs) return;

    const float* init_im = planeA;
    const float* init_re = planeB;

    // ws layout: cnt (NT*64B = 256KB) | lst (NT*MAXQ*4B = 1MB) | par (2MB)
    uint8_t* w8 = (uint8_t*)d_ws;
    uint32_t* cnt = (uint32_t*)w8;
    uint32_t* lst = (uint32_t*)(w8 + (size_t)NT * CPAD * sizeof(uint32_t));
    float4*   par = (float4*)(w8 + (size_t)NT * CPAD * sizeof(uint32_t)
                                 + (size_t)NT * MAXQ * sizeof(uint32_t));

    gf_zero<<<(NT * CPAD) / (4 * 256), 256, 0, stream>>>((uint4*)cnt);

    gf_bin<<<NG / 128, 128, 0, stream>>>(means, chol, weights, cnt, lst, par);
    gf_tiles<<<NT, 256, 0, stream>>>(par, cnt, lst, init_re, init_im, rs,
                                     (uint32_t*)d_out);
}